// Round 2
// baseline (295.787 us; speedup 1.0000x reference)
//
#include <hip/hip_runtime.h>
#include <hip/hip_bf16.h>

#define B_ 4
#define S_ 2048
#define E_ 1024
#define H_ 16
#define D_ 64
#define QSCALE 0.18033688011112042f  // (1/8) * log2(e) : softmax in exp2 domain

typedef __attribute__((ext_vector_type(8))) short bf16x8;   // 8 bf16 (4 VGPRs)
typedef __attribute__((ext_vector_type(4))) float f32x4;    // 16x16 C/D frag
typedef __attribute__((ext_vector_type(16))) float f32x16;  // 32x32 C/D frag

__device__ __forceinline__ f32x4 mfma16(bf16x8 a, bf16x8 b, f32x4 c) {
    return __builtin_amdgcn_mfma_f32_16x16x32_bf16(a, b, c, 0, 0, 0);
}
__device__ __forceinline__ f32x16 mfma32(bf16x8 a, bf16x8 b, f32x16 c) {
    return __builtin_amdgcn_mfma_f32_32x32x16_bf16(a, b, c, 0, 0, 0);
}
__device__ __forceinline__ short f2bs(float f) {
    __hip_bfloat16 h = __float2bfloat16(f);
    return *reinterpret_cast<short*>(&h);
}

// async global->LDS, 16B per lane, wave-uniform LDS base (dest = base + lane*16)
__device__ __forceinline__ void gl16(const void* g, void* l) {
    __builtin_amdgcn_global_load_lds(
        (const __attribute__((address_space(1))) void*)g,
        (__attribute__((address_space(3))) void*)l, 16, 0, 0);
}

// slab strides (shorts). Slab = one 8-wide k-chunk of all rows. Padless:
// global_load_lds staging does no ds_writes, so write-conflict pads are gone.
#define XSLAB 1024   // 128 rows * 8
#define WSLAB 1536   // 192 rows * 8
#define PSLAB 1024   // out_proj slabs

// ---------------------------------------------------------------------------
// Transpose-convert Wq/Wk/Wv (per head [1024][64] fp32) -> WT[48][64][1024] bf16
// Blocks >= 768: convert x [8192][1024] fp32 -> xb bf16 (1024 blocks x 8192 elem)
// ---------------------------------------------------------------------------
__global__ __launch_bounds__(256) void conv_wqkv(
    const float* __restrict__ Wq, const float* __restrict__ Wk,
    const float* __restrict__ Wv, short* __restrict__ WT,
    const float* __restrict__ x, short* __restrict__ xb)
{
    __shared__ float T[64][65];
    const int tid = threadIdx.x;
    if (blockIdx.x >= 768) {
        const int c = blockIdx.x - 768;
        const float* xs = x + (size_t)c * 8192;
        short* xd = xb + (size_t)c * 8192;
        #pragma unroll
        for (int it = 0; it < 4; ++it) {
            const int off = it * 2048 + tid * 8;
            const float4 a = *(const float4*)&xs[off];
            const float4 b = *(const float4*)&xs[off + 4];
            bf16x8 pk;
            pk[0] = f2bs(a.x); pk[1] = f2bs(a.y); pk[2] = f2bs(a.z); pk[3] = f2bs(a.w);
            pk[4] = f2bs(b.x); pk[5] = f2bs(b.y); pk[6] = f2bs(b.z); pk[7] = f2bs(b.w);
            *(bf16x8*)&xd[off] = pk;
        }
        return;
    }
    const int mat = blockIdx.x >> 4;
    const int kt  = blockIdx.x & 15;
    const int which = mat >> 4, h = mat & 15;
    const float* src = (which == 0 ? Wq : which == 1 ? Wk : Wv) + (size_t)h * E_ * D_;
    const int k0 = kt * 64;
    #pragma unroll
    for (int it = 0; it < 4; ++it) {
        int lin = tid + it * 256;
        int kr = lin >> 4, dc = (lin & 15) * 4;
        const float4 v = *(const float4*)&src[(size_t)(k0 + kr) * D_ + dc];
        T[kr][dc] = v.x; T[kr][dc + 1] = v.y; T[kr][dc + 2] = v.z; T[kr][dc + 3] = v.w;
    }
    __syncthreads();
    #pragma unroll
    for (int it = 0; it < 4; ++it) {
        int lin = tid + it * 256;
        int dr = lin >> 4, kc = (lin & 15) * 4;
        ushort4 o;
        o.x = (unsigned short)f2bs(T[kc][dr]);
        o.y = (unsigned short)f2bs(T[kc + 1][dr]);
        o.z = (unsigned short)f2bs(T[kc + 2][dr]);
        o.w = (unsigned short)f2bs(T[kc + 3][dr]);
        *(ushort4*)&WT[((size_t)mat * 64 + dr) * E_ + k0 + kc] = o;
    }
}

// ---------------------------------------------------------------------------
// Transpose-convert Wp [1024][1024] fp32 -> WpT[n][k] bf16
// ---------------------------------------------------------------------------
__global__ __launch_bounds__(256) void conv_wp(
    const float* __restrict__ Wp, short* __restrict__ WpT)
{
    const int ktile = blockIdx.x & 15, ntile = blockIdx.x >> 4;
    const int k0 = ktile * 64, n0 = ntile * 64;
    __shared__ float T[64][65];
    const int tid = threadIdx.x;
    #pragma unroll
    for (int it = 0; it < 4; ++it) {
        int lin = tid + it * 256;
        int kr = lin >> 4, nc = (lin & 15) * 4;
        const float4 v = *(const float4*)&Wp[(size_t)(k0 + kr) * E_ + n0 + nc];
        T[kr][nc] = v.x; T[kr][nc + 1] = v.y; T[kr][nc + 2] = v.z; T[kr][nc + 3] = v.w;
    }
    __syncthreads();
    #pragma unroll
    for (int it = 0; it < 4; ++it) {
        int lin = tid + it * 256;
        int nr = lin >> 4, kc = (lin & 15) * 4;
        ushort4 o;
        o.x = (unsigned short)f2bs(T[kc][nr]);
        o.y = (unsigned short)f2bs(T[kc + 1][nr]);
        o.z = (unsigned short)f2bs(T[kc + 2][nr]);
        o.w = (unsigned short)f2bs(T[kc + 3][nr]);
        *(ushort4*)&WpT[(size_t)(n0 + nr) * E_ + k0 + kc] = o;
    }
}

// ---------------------------------------------------------------------------
// Fused QKV projection, 32x32x16 MFMA. Block 128 rows x 192 cols (3 mats),
// wave = 64 rows x 96 cols (2x3 frag32). BK=64, global_load_lds staging
// (no staging VGPRs, no cvt, no ds_writes), single-buffered two-barrier loop.
// V stored transposed [B,H,D,S].
// ---------------------------------------------------------------------------
__global__ __launch_bounds__(256, 3) void qkv_fused(
    const short* __restrict__ xb, const short* __restrict__ WT,
    const float* __restrict__ bq, const float* __restrict__ bk,
    const float* __restrict__ bv,
    short* __restrict__ Qw, short* __restrict__ Kw, short* __restrict__ VTw)
{
    const int h = blockIdx.y;
    const int m0 = blockIdx.x * 128;
    __shared__ short SM[8 * XSLAB + 8 * WSLAB];   // 40 KB exactly
    short* Xs = SM;
    short* Ws = SM + 8 * XSLAB;

    const int tid = threadIdx.x;
    const int lane = tid & 63, w = tid >> 6;
    const int wm = w & 1, wn = w >> 1;            // wave m-half / n-half
    const int l31 = lane & 31, hi = lane >> 5;

    f32x16 acc[2][3];
    #pragma unroll
    for (int mf = 0; mf < 2; ++mf)
        #pragma unroll
        for (int nf = 0; nf < 3; ++nf)
            #pragma unroll
            for (int i = 0; i < 16; ++i) acc[mf][nf][i] = 0.f;

    for (int k0 = 0; k0 < E_; k0 += 64) {
        // ---- async stage: X tile (8 slabs x 128 rows), 16B/lane -------------
        #pragma unroll
        for (int it = 0; it < 4; ++it) {
            const int u = it * 256 + tid;
            const int s = u >> 7, r = u & 127;          // per-lane global coords
            const int ub = it * 256 + (tid & 192);      // wave-uniform LDS base
            gl16(&xb[(size_t)(m0 + r) * E_ + k0 + s * 8],
                 &Xs[(ub >> 7) * XSLAB + (ub & 127) * 8]);
        }
        // ---- async stage: W rows 0..127 (Q,K mats) --------------------------
        #pragma unroll
        for (int it = 0; it < 4; ++it) {
            const int u = it * 256 + tid;
            const int s = u >> 7, r = u & 127;
            const int ub = it * 256 + (tid & 192);
            const int rg = ((r >> 6) * 16 + h) * 64 + (r & 63);
            gl16(&WT[(size_t)rg * E_ + k0 + s * 8],
                 &Ws[(ub >> 7) * WSLAB + (ub & 127) * 8]);
        }
        // ---- async stage: W rows 128..191 (V mat) ---------------------------
        #pragma unroll
        for (int it = 0; it < 2; ++it) {
            const int u = it * 256 + tid;
            const int s = u >> 6;
            const int ub = it * 256 + (tid & 192);
            const int rg = (32 + h) * 64 + (u & 63);
            gl16(&WT[(size_t)rg * E_ + k0 + s * 8],
                 &Ws[(ub >> 6) * WSLAB + 1024]);       // row 128 base
        }
        __syncthreads();   // compiler drains vmcnt(0) before s_barrier
        // ---- 4 k-steps x 6 mfma32 ------------------------------------------
        #pragma unroll
        for (int ks = 0; ks < 4; ++ks) {
            const int ccr = ks * 2 + hi;
            bf16x8 a[2], b[3];
            #pragma unroll
            for (int mf = 0; mf < 2; ++mf)
                a[mf] = *(const bf16x8*)&Xs[ccr * XSLAB + (wm * 64 + mf * 32 + l31) * 8];
            #pragma unroll
            for (int nf = 0; nf < 3; ++nf)
                b[nf] = *(const bf16x8*)&Ws[ccr * WSLAB + (wn * 96 + nf * 32 + l31) * 8];
            #pragma unroll
            for (int mf = 0; mf < 2; ++mf)
                #pragma unroll
                for (int nf = 0; nf < 3; ++nf)
                    acc[mf][nf] = mfma32(a[mf], b[nf], acc[mf][nf]);
        }
        __syncthreads();   // all reads done before next stage overwrites
    }

    // epilogue. C/D 32-shape: col=l31, row=(reg&3)+8*(reg>>2)+4*hi
    const int bb = m0 >> 11;
    const int s0 = m0 & (S_ - 1);
    const size_t qkbase = ((size_t)bb * H_ + h) * S_;
    short* Vr = SM;                                // reuse (size 64*136 shorts)
    #pragma unroll
    for (int mf = 0; mf < 2; ++mf)
        #pragma unroll
        for (int nf = 0; nf < 3; ++nf) {
            const int ng = wn * 96 + nf * 32;      // wave-uniform
            const int mat = ng >> 6;
            const int d = (ng & 63) + l31;
            const int sl0 = wm * 64 + mf * 32 + 4 * hi;
            if (mat == 0) {
                const float bb_ = bq[h * D_ + d];
                #pragma unroll
                for (int rg = 0; rg < 16; ++rg) {
                    int s = s0 + sl0 + (rg & 3) + 8 * (rg >> 2);
                    Qw[(qkbase + s) * D_ + d] = f2bs((acc[mf][nf][rg] + bb_) * QSCALE);
                }
            } else if (mat == 1) {
                const float bb_ = bk[h * D_ + d];
                #pragma unroll
                for (int rg = 0; rg < 16; ++rg) {
                    int s = s0 + sl0 + (rg & 3) + 8 * (rg >> 2);
                    Kw[(qkbase + s) * D_ + d] = f2bs(acc[mf][nf][rg] + bb_);
                }
            } else {
                const float bb_ = bv[h * D_ + d];
                #pragma unroll
                for (int rg = 0; rg < 16; ++rg) {
                    int sl = sl0 + (rg & 3) + 8 * (rg >> 2);
                    Vr[d * 136 + sl] = f2bs(acc[mf][nf][rg] + bb_);
                }
            }
        }
    __syncthreads();
    const size_t vbase = ((size_t)bb * H_ + h) * (size_t)D_ * S_;
    const int sc = tid & 15, dr = tid >> 4;
    #pragma unroll
    for (int it = 0; it < 4; ++it) {
        int d = it * 16 + dr;
        *(bf16x8*)&VTw[vbase + (size_t)d * S_ + s0 + sc * 8] =
            *(const bf16x8*)&Vr[d * 136 + sc * 8];
    }
}

// ---------------------------------------------------------------------------
// Flash attention (round-3 proven version, unchanged). Fixed-max softmax,
// paired q-tiles, double-buffered K/V LDS with register prefetch.
// ---------------------------------------------------------------------------
__global__ __launch_bounds__(256, 2) void attn(
    const short* __restrict__ Qw, const short* __restrict__ Kw,
    const short* __restrict__ VTw, short* __restrict__ Ow)
{
    const int jj = blockIdx.x;                    // 0..7
    const int bh = blockIdx.y;
    const int b = bh >> 4, h = bh & 15;
    const size_t kbase = ((size_t)b * H_ + h) * (size_t)S_ * D_;
    const size_t vbase = ((size_t)b * H_ + h) * (size_t)D_ * S_;

    __shared__ short Qs[128 * 72];
    __shared__ short Ks[2][64 * 72];
    __shared__ short Vt[2][64 * 72];

    const int tid = threadIdx.x;
    const int lane = tid & 63, w = tid >> 6;
    const int l15 = lane & 15, qd = lane >> 4;

    const int r0s = tid >> 3;
    const int c0s = (tid & 7) * 8;
    const int r1s = r0s + 32;

    #pragma unroll
    for (int phase = 0; phase < 2; ++phase) {
        const int qt = phase ? jj : (15 - jj);

        #pragma unroll
        for (int it = 0; it < 4; ++it) {
            int row = w * 32 + it * 8 + (lane >> 3);
            int cb = (lane & 7) * 8;
            *(bf16x8*)&Qs[row * 72 + cb] =
                *(const bf16x8*)&Qw[kbase + (size_t)(qt * 128 + row) * D_ + cb];
        }
        asm volatile("s_waitcnt lgkmcnt(0)" ::: "memory");
        bf16x8 qf[2][2];
        #pragma unroll
        for (int mi = 0; mi < 2; ++mi)
            #pragma unroll
            for (int t = 0; t < 2; ++t)
                qf[mi][t] = *(const bf16x8*)&Qs[(w * 32 + mi * 16 + l15) * 72 + t * 32 + qd * 8];

        f32x4 zero = {0.f, 0.f, 0.f, 0.f};
        f32x4 oacc[2][4];
        float lrow[2][4];
        #pragma unroll
        for (int mi = 0; mi < 2; ++mi) {
            #pragma unroll
            for (int c = 0; c < 4; ++c) oacc[mi][c] = zero;
            #pragma unroll
            for (int r = 0; r < 4; ++r) lrow[mi][r] = 0.f;
        }

        const int nkt = (qt + 1) * 2;
        bf16x8 kr0, kr1, vr0, vr1;
        kr0 = *(const bf16x8*)&Kw[kbase + (size_t)r0s * D_ + c0s];
        kr1 = *(const bf16x8*)&Kw[kbase + (size_t)r1s * D_ + c0s];
        vr0 = *(const bf16x8*)&VTw[vbase + (size_t)r0s * S_ + c0s];
        vr1 = *(const bf16x8*)&VTw[vbase + (size_t)r1s * S_ + c0s];
        *(bf16x8*)&Ks[0][r0s * 72 + c0s] = kr0;
        *(bf16x8*)&Ks[0][r1s * 72 + c0s] = kr1;
        *(bf16x8*)&Vt[0][r0s * 72 + c0s] = vr0;
        *(bf16x8*)&Vt[0][r1s * 72 + c0s] = vr1;
        __syncthreads();

        int p = 0;
        for (int kt = 0; kt < nkt; ++kt) {
            const bool pre = (kt + 1 < nkt);
            if (pre) {
                kr0 = *(const bf16x8*)&Kw[kbase + (size_t)((kt + 1) * 64 + r0s) * D_ + c0s];
                kr1 = *(const bf16x8*)&Kw[kbase + (size_t)((kt + 1) * 64 + r1s) * D_ + c0s];
                vr0 = *(const bf16x8*)&VTw[vbase + (size_t)r0s * S_ + (kt + 1) * 64 + c0s];
                vr1 = *(const bf16x8*)&VTw[vbase + (size_t)r1s * S_ + (kt + 1) * 64 + c0s];
            }
            f32x4 sc[2][4];
            #pragma unroll
            for (int mi = 0; mi < 2; ++mi)
                #pragma unroll
                for (int c = 0; c < 4; ++c) sc[mi][c] = zero;
            #pragma unroll
            for (int t = 0; t < 2; ++t)
                #pragma unroll
                for (int c = 0; c < 4; ++c) {
                    bf16x8 bk = *(const bf16x8*)&Ks[p][(c * 16 + l15) * 72 + t * 32 + qd * 8];
                    sc[0][c] = mfma16(qf[0][t], bk, sc[0][c]);
                    sc[1][c] = mfma16(qf[1][t], bk, sc[1][c]);
                }
            #pragma unroll
            for (int mi = 0; mi < 2; ++mi) {
                const int fr = qt * 128 + w * 32 + mi * 16;
                if (kt * 64 + 63 > fr) {
                    #pragma unroll
                    for (int c = 0; c < 4; ++c) {
                        int col = kt * 64 + c * 16 + l15;
                        #pragma unroll
                        for (int r = 0; r < 4; ++r)
                            if (col > fr + qd * 4 + r) sc[mi][c][r] = -1e30f;
                    }
                }
                #pragma unroll
                for (int c = 0; c < 4; ++c)
                    #pragma unroll
                    for (int r = 0; r < 4; ++r) {
                        float pv = __builtin_amdgcn_exp2f(sc[mi][c][r]);
                        lrow[mi][r] += pv;
                        Qs[(w * 32 + mi * 16 + qd * 4 + r) * 72 + c * 16 + l15] = f2bs(pv);
                    }
            }
            asm volatile("s_waitcnt lgkmcnt(0)" ::: "memory");
            #pragma unroll
            for (int t = 0; t < 2; ++t) {
                bf16x8 ap0 = *(const bf16x8*)&Qs[(w * 32 + l15) * 72 + t * 32 + qd * 8];
                bf16x8 ap1 = *(const bf16x8*)&Qs[(w * 32 + 16 + l15) * 72 + t * 32 + qd * 8];
                #pragma unroll
                for (int c = 0; c < 4; ++c) {
                    bf16x8 bv = *(const bf16x8*)&Vt[p][(c * 16 + l15) * 72 + t * 32 + qd * 8];
                    oacc[0][c] = mfma16(ap0, bv, oacc[0][c]);
                    oacc[1][c] = mfma16(ap1, bv, oacc[1][c]);
                }
            }
            if (pre) {
                *(bf16x8*)&Ks[1 - p][r0s * 72 + c0s] = kr0;
                *(bf16x8*)&Ks[1 - p][r1s * 72 + c0s] = kr1;
                *(bf16x8*)&Vt[1 - p][r0s * 72 + c0s] = vr0;
                *(bf16x8*)&Vt[1 - p][r1s * 72 + c0s] = vr1;
            }
            __syncthreads();
            p ^= 1;
        }

        #pragma unroll
        for (int mi = 0; mi < 2; ++mi) {
            float inv[4];
            #pragma unroll
            for (int r = 0; r < 4; ++r) {
                float l = lrow[mi][r];
                l += __shfl_xor(l, 1);
                l += __shfl_xor(l, 2);
                l += __shfl_xor(l, 4);
                l += __shfl_xor(l, 8);
                inv[r] = 1.f / l;
            }
            #pragma unroll
            for (int c = 0; c < 4; ++c)
                #pragma unroll
                for (int r = 0; r < 4; ++r) {
                    int s = qt * 128 + w * 32 + mi * 16 + qd * 4 + r;
                    Ow[((size_t)b * S_ + s) * (H_ * D_) + h * D_ + c * 16 + l15] =
                        f2bs(oacc[mi][c][r] * inv[r]);
                }
        }
    }
}

// ---------------------------------------------------------------------------
// Output projection, 32x32x16 MFMA. Block 128x128, wave 64x64 (2x2 frag32),
// BK=64, global_load_lds staging, single-buffered two-barrier loop.
// ---------------------------------------------------------------------------
__global__ __launch_bounds__(256, 4) void out_proj(
    const short* __restrict__ Oin, const short* __restrict__ WpT,
    const float* __restrict__ bp, float* __restrict__ out)
{
    const int m0 = blockIdx.x * 128;
    const int n0 = blockIdx.y * 128;
    __shared__ short SM2[16 * PSLAB];             // A slabs + B slabs, 32 KB
    short* As = SM2;
    short* Bs = SM2 + 8 * PSLAB;

    const int tid = threadIdx.x;
    const int lane = tid & 63, w = tid >> 6;
    const int wm = w & 1, wn = w >> 1;
    const int l31 = lane & 31, hi = lane >> 5;

    f32x16 acc[2][2];
    #pragma unroll
    for (int mf = 0; mf < 2; ++mf)
        #pragma unroll
        for (int nf = 0; nf < 2; ++nf)
            #pragma unroll
            for (int i = 0; i < 16; ++i) acc[mf][nf][i] = 0.f;

    for (int k0 = 0; k0 < E_; k0 += 64) {
        #pragma unroll
        for (int it = 0; it < 4; ++it) {
            const int u = it * 256 + tid;
            const int s = u >> 7, r = u & 127;
            const int ub = it * 256 + (tid & 192);
            const int lo = (ub >> 7) * PSLAB + (ub & 127) * 8;
            gl16(&Oin[(size_t)(m0 + r) * E_ + k0 + s * 8], &As[lo]);
            gl16(&WpT[(size_t)(n0 + r) * E_ + k0 + s * 8], &Bs[lo]);
        }
        __syncthreads();
        #pragma unroll
        for (int ks = 0; ks < 4; ++ks) {
            const int ccr = ks * 2 + hi;
            bf16x8 a[2], b[2];
            #pragma unroll
            for (int mf = 0; mf < 2; ++mf)
                a[mf] = *(const bf16x8*)&As[ccr * PSLAB + (wm * 64 + mf * 32 + l31) * 8];
            #pragma unroll
            for (int nf = 0; nf < 2; ++nf)
                b[nf] = *(const bf16x8*)&Bs[ccr * PSLAB + (wn * 64 + nf * 32 + l31) * 8];
            #pragma unroll
            for (int mf = 0; mf < 2; ++mf)
                #pragma unroll
                for (int nf = 0; nf < 2; ++nf)
                    acc[mf][nf] = mfma32(a[mf], b[nf], acc[mf][nf]);
        }
        __syncthreads();
    }
    #pragma unroll
    for (int mf = 0; mf < 2; ++mf)
        #pragma unroll
        for (int nf = 0; nf < 2; ++nf) {
            const int n = n0 + wn * 64 + nf * 32 + l31;
            const float bpv = bp[n];
            const int sl0 = wm * 64 + mf * 32 + 4 * hi;
            #pragma unroll
            for (int rg = 0; rg < 16; ++rg) {
                int m = m0 + sl0 + (rg & 3) + 8 * (rg >> 2);
                out[(size_t)m * E_ + n] = acc[mf][nf][rg] + bpv;
            }
        }
}

// ---------------------------------------------------------------------------
extern "C" void kernel_launch(void* const* d_in, const int* in_sizes, int n_in,
                              void* d_out, int out_size, void* d_ws, size_t ws_size,
                              hipStream_t stream)
{
    const float* x  = (const float*)d_in[0];
    const float* Wq = (const float*)d_in[1];
    const float* bq = (const float*)d_in[2];
    const float* Wk = (const float*)d_in[3];
    const float* bk = (const float*)d_in[4];
    const float* Wv = (const float*)d_in[5];
    const float* bv = (const float*)d_in[6];
    const float* Wp = (const float*)d_in[7];
    const float* bp = (const float*)d_in[8];
    float* out = (float*)d_out;

    const size_t nQKV = (size_t)B_ * H_ * S_ * D_;   // 8,388,608 bf16 elements
    short* Qw   = (short*)d_ws;          // [B,H,S,D]; later reused for WpT
    short* Kw   = Qw + nQKV;             // [B,H,S,D]
    short* VTw  = Kw + nQKV;             // [B,H,D,S]
    short* WT   = VTw + nQKV;            // [48][64][1024] bf16 (3,145,728 shorts)
    short* xb   = WT + (size_t)48 * 64 * E_;  // x as bf16 [8192][1024]
    short* Ow   = xb;                    // xb dead after qkv_fused; attn writes Ow here
    short* WpT  = Qw;                    // Qw dead after attn

    conv_wqkv<<<dim3(1792), 256, 0, stream>>>(Wq, Wk, Wv, WT, x, xb);
    qkv_fused<<<dim3(64, 16), 256, 0, stream>>>(xb, WT, bq, bk, bv, Qw, Kw, VTw);
    attn<<<dim3(8, 64), 256, 0, stream>>>(Qw, Kw, VTw, Ow);
    conv_wp<<<dim3(256), 256, 0, stream>>>(Wp, WpT);
    out_proj<<<dim3(64, 8), 256, 0, stream>>>(Ow, WpT, bp, out);
}

// Round 3
// 290.660 us; speedup vs baseline: 1.0176x; 1.0176x over previous
//
#include <hip/hip_runtime.h>
#include <hip/hip_bf16.h>

#define B_ 4
#define S_ 2048
#define E_ 1024
#define H_ 16
#define D_ 64
#define QSCALE 0.18033688011112042f  // (1/8) * log2(e) : softmax in exp2 domain

typedef __attribute__((ext_vector_type(8))) short bf16x8;   // 8 bf16 (4 VGPRs)
typedef __attribute__((ext_vector_type(4))) float f32x4;    // 16x16 C/D frag
typedef __attribute__((ext_vector_type(16))) float f32x16;  // 32x32 C/D frag

__device__ __forceinline__ f32x4 mfma16(bf16x8 a, bf16x8 b, f32x4 c) {
    return __builtin_amdgcn_mfma_f32_16x16x32_bf16(a, b, c, 0, 0, 0);
}
__device__ __forceinline__ f32x16 mfma32(bf16x8 a, bf16x8 b, f32x16 c) {
    return __builtin_amdgcn_mfma_f32_32x32x16_bf16(a, b, c, 0, 0, 0);
}
__device__ __forceinline__ short f2bs(float f) {
    __hip_bfloat16 h = __float2bfloat16(f);
    return *reinterpret_cast<short*>(&h);
}

// async global->LDS, 16B per lane, wave-uniform LDS base (dest = base + lane*16)
__device__ __forceinline__ void gl16(const void* g, void* l) {
    __builtin_amdgcn_global_load_lds(
        (const __attribute__((address_space(1))) void*)g,
        (__attribute__((address_space(3))) void*)l, 16, 0, 0);
}

// slab strides (shorts). Slab = one 8-wide k-chunk of all rows. Padless:
// global_load_lds staging does no ds_writes, so write-conflict pads are gone.
#define XSLAB 1024   // 128 rows * 8
#define WSLAB 1536   // 192 rows * 8
#define PSLAB 1024   // out_proj slabs
#define QBUF  20480  // 8*XSLAB + 8*WSLAB shorts = 40 KB per buffer
#define PBUF  16384  // 16*PSLAB shorts = 32 KB per buffer

// ---------------------------------------------------------------------------
// Transpose-convert Wq/Wk/Wv (per head [1024][64] fp32) -> WT[48][64][1024] bf16
// Blocks >= 768: convert x [8192][1024] fp32 -> xb bf16 (1024 blocks x 8192 elem)
// ---------------------------------------------------------------------------
__global__ __launch_bounds__(256) void conv_wqkv(
    const float* __restrict__ Wq, const float* __restrict__ Wk,
    const float* __restrict__ Wv, short* __restrict__ WT,
    const float* __restrict__ x, short* __restrict__ xb)
{
    __shared__ float T[64][65];
    const int tid = threadIdx.x;
    if (blockIdx.x >= 768) {
        const int c = blockIdx.x - 768;
        const float* xs = x + (size_t)c * 8192;
        short* xd = xb + (size_t)c * 8192;
        #pragma unroll
        for (int it = 0; it < 4; ++it) {
            const int off = it * 2048 + tid * 8;
            const float4 a = *(const float4*)&xs[off];
            const float4 b = *(const float4*)&xs[off + 4];
            bf16x8 pk;
            pk[0] = f2bs(a.x); pk[1] = f2bs(a.y); pk[2] = f2bs(a.z); pk[3] = f2bs(a.w);
            pk[4] = f2bs(b.x); pk[5] = f2bs(b.y); pk[6] = f2bs(b.z); pk[7] = f2bs(b.w);
            *(bf16x8*)&xd[off] = pk;
        }
        return;
    }
    const int mat = blockIdx.x >> 4;
    const int kt  = blockIdx.x & 15;
    const int which = mat >> 4, h = mat & 15;
    const float* src = (which == 0 ? Wq : which == 1 ? Wk : Wv) + (size_t)h * E_ * D_;
    const int k0 = kt * 64;
    #pragma unroll
    for (int it = 0; it < 4; ++it) {
        int lin = tid + it * 256;
        int kr = lin >> 4, dc = (lin & 15) * 4;
        const float4 v = *(const float4*)&src[(size_t)(k0 + kr) * D_ + dc];
        T[kr][dc] = v.x; T[kr][dc + 1] = v.y; T[kr][dc + 2] = v.z; T[kr][dc + 3] = v.w;
    }
    __syncthreads();
    #pragma unroll
    for (int it = 0; it < 4; ++it) {
        int lin = tid + it * 256;
        int dr = lin >> 4, kc = (lin & 15) * 4;
        ushort4 o;
        o.x = (unsigned short)f2bs(T[kc][dr]);
        o.y = (unsigned short)f2bs(T[kc + 1][dr]);
        o.z = (unsigned short)f2bs(T[kc + 2][dr]);
        o.w = (unsigned short)f2bs(T[kc + 3][dr]);
        *(ushort4*)&WT[((size_t)mat * 64 + dr) * E_ + k0 + kc] = o;
    }
}

// ---------------------------------------------------------------------------
// Transpose-convert Wp [1024][1024] fp32 -> WpT[n][k] bf16
// ---------------------------------------------------------------------------
__global__ __launch_bounds__(256) void conv_wp(
    const float* __restrict__ Wp, short* __restrict__ WpT)
{
    const int ktile = blockIdx.x & 15, ntile = blockIdx.x >> 4;
    const int k0 = ktile * 64, n0 = ntile * 64;
    __shared__ float T[64][65];
    const int tid = threadIdx.x;
    #pragma unroll
    for (int it = 0; it < 4; ++it) {
        int lin = tid + it * 256;
        int kr = lin >> 4, nc = (lin & 15) * 4;
        const float4 v = *(const float4*)&Wp[(size_t)(k0 + kr) * E_ + n0 + nc];
        T[kr][nc] = v.x; T[kr][nc + 1] = v.y; T[kr][nc + 2] = v.z; T[kr][nc + 3] = v.w;
    }
    __syncthreads();
    #pragma unroll
    for (int it = 0; it < 4; ++it) {
        int lin = tid + it * 256;
        int nr = lin >> 4, kc = (lin & 15) * 4;
        ushort4 o;
        o.x = (unsigned short)f2bs(T[kc][nr]);
        o.y = (unsigned short)f2bs(T[kc + 1][nr]);
        o.z = (unsigned short)f2bs(T[kc + 2][nr]);
        o.w = (unsigned short)f2bs(T[kc + 3][nr]);
        *(ushort4*)&WpT[(size_t)(n0 + nr) * E_ + k0 + kc] = o;
    }
}

// ---------------------------------------------------------------------------
// Fused QKV projection, 32x32x16 MFMA. Block 128 rows x 192 cols (3 mats),
// wave = 64 rows x 96 cols (2x3 frag32). BK=64 global_load_lds staging into
// DOUBLE-buffered LDS, 2-deep prefetch, counted vmcnt(10) (never drained in
// loop), raw s_barrier (no compiler vmcnt(0) drain). V stored [B,H,D,S].
// ---------------------------------------------------------------------------
__global__ __launch_bounds__(256, 2) void qkv_fused(
    const short* __restrict__ xb, const short* __restrict__ WT,
    const float* __restrict__ bq, const float* __restrict__ bk,
    const float* __restrict__ bv,
    short* __restrict__ Qw, short* __restrict__ Kw, short* __restrict__ VTw)
{
    const int h = blockIdx.y;
    const int m0 = blockIdx.x * 128;
    __shared__ short SM[2 * QBUF];                // 80 KB: two 40 KB buffers

    const int tid = threadIdx.x;
    const int lane = tid & 63, w = tid >> 6;
    const int wm = w & 1, wn = w >> 1;            // wave m-half / n-half
    const int l31 = lane & 31, hi = lane >> 5;

    f32x16 acc[2][3];
    #pragma unroll
    for (int mf = 0; mf < 2; ++mf)
        #pragma unroll
        for (int nf = 0; nf < 3; ++nf)
            #pragma unroll
            for (int i = 0; i < 16; ++i) acc[mf][nf][i] = 0.f;

    // stage one K-tile (10 gl16 units) into buffer pb
    auto stage = [&](int kt, int pb) {
        const int k0 = kt * 64;
        short* Xs = SM + pb * QBUF;
        short* Ws = Xs + 8 * XSLAB;
        #pragma unroll
        for (int it = 0; it < 4; ++it) {          // X tile: 8 slabs x 128 rows
            const int u = it * 256 + tid;
            const int s = u >> 7, r = u & 127;
            const int ub = it * 256 + (tid & 192);
            gl16(&xb[(size_t)(m0 + r) * E_ + k0 + s * 8],
                 &Xs[(ub >> 7) * XSLAB + (ub & 127) * 8]);
        }
        #pragma unroll
        for (int it = 0; it < 4; ++it) {          // W rows 0..127 (Q,K mats)
            const int u = it * 256 + tid;
            const int s = u >> 7, r = u & 127;
            const int ub = it * 256 + (tid & 192);
            const int rg = ((r >> 6) * 16 + h) * 64 + (r & 63);
            gl16(&WT[(size_t)rg * E_ + k0 + s * 8],
                 &Ws[(ub >> 7) * WSLAB + (ub & 127) * 8]);
        }
        #pragma unroll
        for (int it = 0; it < 2; ++it) {          // W rows 128..191 (V mat)
            const int u = it * 256 + tid;
            const int s = u >> 6;
            const int ub = it * 256 + (tid & 192);
            const int rg = (32 + h) * 64 + (u & 63);
            gl16(&WT[(size_t)rg * E_ + k0 + s * 8],
                 &Ws[(ub >> 6) * WSLAB + 1024]); // row-128 base
        }
    };

    stage(0, 0);
    stage(1, 1);
    __builtin_amdgcn_sched_barrier(0);

    int p = 0;
    for (int kt = 0; kt < 16; ++kt) {
        // wait for tile kt only; tile kt+1's 10 loads stay in flight
        if (kt < 15) { asm volatile("s_waitcnt vmcnt(10)" ::: "memory"); }
        else         { asm volatile("s_waitcnt vmcnt(0)"  ::: "memory"); }
        __builtin_amdgcn_sched_barrier(0);
        __builtin_amdgcn_s_barrier();             // all waves' tile-kt loads done
        __builtin_amdgcn_sched_barrier(0);

        const short* Xs = SM + p * QBUF;
        const short* Ws = Xs + 8 * XSLAB;
        __builtin_amdgcn_s_setprio(1);
        #pragma unroll
        for (int ks = 0; ks < 4; ++ks) {
            const int ccr = ks * 2 + hi;
            bf16x8 a[2], b[3];
            #pragma unroll
            for (int mf = 0; mf < 2; ++mf)
                a[mf] = *(const bf16x8*)&Xs[ccr * XSLAB + (wm * 64 + mf * 32 + l31) * 8];
            #pragma unroll
            for (int nf = 0; nf < 3; ++nf)
                b[nf] = *(const bf16x8*)&Ws[ccr * WSLAB + (wn * 96 + nf * 32 + l31) * 8];
            #pragma unroll
            for (int mf = 0; mf < 2; ++mf)
                #pragma unroll
                for (int nf = 0; nf < 3; ++nf)
                    acc[mf][nf] = mfma32(a[mf], b[nf], acc[mf][nf]);
        }
        __builtin_amdgcn_s_setprio(0);
        __builtin_amdgcn_sched_barrier(0);
        __builtin_amdgcn_s_barrier();             // all reads of buf p complete
        __builtin_amdgcn_sched_barrier(0);
        if (kt + 2 < 16) stage(kt + 2, p);        // refill the buffer just freed
        __builtin_amdgcn_sched_barrier(0);
        p ^= 1;
    }

    // epilogue. C/D 32-shape: col=l31, row=(reg&3)+8*(reg>>2)+4*hi
    // (vmcnt==0 here; last raw barrier guarantees all LDS reads done -> SM reusable)
    const int bb = m0 >> 11;
    const int s0 = m0 & (S_ - 1);
    const size_t qkbase = ((size_t)bb * H_ + h) * S_;
    short* Vr = SM;                                // reuse (size 64*136 shorts)
    #pragma unroll
    for (int mf = 0; mf < 2; ++mf)
        #pragma unroll
        for (int nf = 0; nf < 3; ++nf) {
            const int ng = wn * 96 + nf * 32;      // wave-uniform
            const int mat = ng >> 6;
            const int d = (ng & 63) + l31;
            const int sl0 = wm * 64 + mf * 32 + 4 * hi;
            if (mat == 0) {
                const float bb_ = bq[h * D_ + d];
                #pragma unroll
                for (int rg = 0; rg < 16; ++rg) {
                    int s = s0 + sl0 + (rg & 3) + 8 * (rg >> 2);
                    Qw[(qkbase + s) * D_ + d] = f2bs((acc[mf][nf][rg] + bb_) * QSCALE);
                }
            } else if (mat == 1) {
                const float bb_ = bk[h * D_ + d];
                #pragma unroll
                for (int rg = 0; rg < 16; ++rg) {
                    int s = s0 + sl0 + (rg & 3) + 8 * (rg >> 2);
                    Kw[(qkbase + s) * D_ + d] = f2bs(acc[mf][nf][rg] + bb_);
                }
            } else {
                const float bb_ = bv[h * D_ + d];
                #pragma unroll
                for (int rg = 0; rg < 16; ++rg) {
                    int sl = sl0 + (rg & 3) + 8 * (rg >> 2);
                    Vr[d * 136 + sl] = f2bs(acc[mf][nf][rg] + bb_);
                }
            }
        }
    __syncthreads();
    const size_t vbase = ((size_t)bb * H_ + h) * (size_t)D_ * S_;
    const int sc = tid & 15, dr = tid >> 4;
    #pragma unroll
    for (int it = 0; it < 4; ++it) {
        int d = it * 16 + dr;
        *(bf16x8*)&VTw[vbase + (size_t)d * S_ + s0 + sc * 8] =
            *(const bf16x8*)&Vr[d * 136 + sc * 8];
    }
}

// ---------------------------------------------------------------------------
// Flash attention (round-3 proven version, unchanged). Fixed-max softmax,
// paired q-tiles, double-buffered K/V LDS with register prefetch.
// ---------------------------------------------------------------------------
__global__ __launch_bounds__(256, 2) void attn(
    const short* __restrict__ Qw, const short* __restrict__ Kw,
    const short* __restrict__ VTw, short* __restrict__ Ow)
{
    const int jj = blockIdx.x;                    // 0..7
    const int bh = blockIdx.y;
    const int b = bh >> 4, h = bh & 15;
    const size_t kbase = ((size_t)b * H_ + h) * (size_t)S_ * D_;
    const size_t vbase = ((size_t)b * H_ + h) * (size_t)D_ * S_;

    __shared__ short Qs[128 * 72];
    __shared__ short Ks[2][64 * 72];
    __shared__ short Vt[2][64 * 72];

    const int tid = threadIdx.x;
    const int lane = tid & 63, w = tid >> 6;
    const int l15 = lane & 15, qd = lane >> 4;

    const int r0s = tid >> 3;
    const int c0s = (tid & 7) * 8;
    const int r1s = r0s + 32;

    #pragma unroll
    for (int phase = 0; phase < 2; ++phase) {
        const int qt = phase ? jj : (15 - jj);

        #pragma unroll
        for (int it = 0; it < 4; ++it) {
            int row = w * 32 + it * 8 + (lane >> 3);
            int cb = (lane & 7) * 8;
            *(bf16x8*)&Qs[row * 72 + cb] =
                *(const bf16x8*)&Qw[kbase + (size_t)(qt * 128 + row) * D_ + cb];
        }
        asm volatile("s_waitcnt lgkmcnt(0)" ::: "memory");
        bf16x8 qf[2][2];
        #pragma unroll
        for (int mi = 0; mi < 2; ++mi)
            #pragma unroll
            for (int t = 0; t < 2; ++t)
                qf[mi][t] = *(const bf16x8*)&Qs[(w * 32 + mi * 16 + l15) * 72 + t * 32 + qd * 8];

        f32x4 zero = {0.f, 0.f, 0.f, 0.f};
        f32x4 oacc[2][4];
        float lrow[2][4];
        #pragma unroll
        for (int mi = 0; mi < 2; ++mi) {
            #pragma unroll
            for (int c = 0; c < 4; ++c) oacc[mi][c] = zero;
            #pragma unroll
            for (int r = 0; r < 4; ++r) lrow[mi][r] = 0.f;
        }

        const int nkt = (qt + 1) * 2;
        bf16x8 kr0, kr1, vr0, vr1;
        kr0 = *(const bf16x8*)&Kw[kbase + (size_t)r0s * D_ + c0s];
        kr1 = *(const bf16x8*)&Kw[kbase + (size_t)r1s * D_ + c0s];
        vr0 = *(const bf16x8*)&VTw[vbase + (size_t)r0s * S_ + c0s];
        vr1 = *(const bf16x8*)&VTw[vbase + (size_t)r1s * S_ + c0s];
        *(bf16x8*)&Ks[0][r0s * 72 + c0s] = kr0;
        *(bf16x8*)&Ks[0][r1s * 72 + c0s] = kr1;
        *(bf16x8*)&Vt[0][r0s * 72 + c0s] = vr0;
        *(bf16x8*)&Vt[0][r1s * 72 + c0s] = vr1;
        __syncthreads();

        int p = 0;
        for (int kt = 0; kt < nkt; ++kt) {
            const bool pre = (kt + 1 < nkt);
            if (pre) {
                kr0 = *(const bf16x8*)&Kw[kbase + (size_t)((kt + 1) * 64 + r0s) * D_ + c0s];
                kr1 = *(const bf16x8*)&Kw[kbase + (size_t)((kt + 1) * 64 + r1s) * D_ + c0s];
                vr0 = *(const bf16x8*)&VTw[vbase + (size_t)r0s * S_ + (kt + 1) * 64 + c0s];
                vr1 = *(const bf16x8*)&VTw[vbase + (size_t)r1s * S_ + (kt + 1) * 64 + c0s];
            }
            f32x4 sc[2][4];
            #pragma unroll
            for (int mi = 0; mi < 2; ++mi)
                #pragma unroll
                for (int c = 0; c < 4; ++c) sc[mi][c] = zero;
            #pragma unroll
            for (int t = 0; t < 2; ++t)
                #pragma unroll
                for (int c = 0; c < 4; ++c) {
                    bf16x8 bk = *(const bf16x8*)&Ks[p][(c * 16 + l15) * 72 + t * 32 + qd * 8];
                    sc[0][c] = mfma16(qf[0][t], bk, sc[0][c]);
                    sc[1][c] = mfma16(qf[1][t], bk, sc[1][c]);
                }
            #pragma unroll
            for (int mi = 0; mi < 2; ++mi) {
                const int fr = qt * 128 + w * 32 + mi * 16;
                if (kt * 64 + 63 > fr) {
                    #pragma unroll
                    for (int c = 0; c < 4; ++c) {
                        int col = kt * 64 + c * 16 + l15;
                        #pragma unroll
                        for (int r = 0; r < 4; ++r)
                            if (col > fr + qd * 4 + r) sc[mi][c][r] = -1e30f;
                    }
                }
                #pragma unroll
                for (int c = 0; c < 4; ++c)
                    #pragma unroll
                    for (int r = 0; r < 4; ++r) {
                        float pv = __builtin_amdgcn_exp2f(sc[mi][c][r]);
                        lrow[mi][r] += pv;
                        Qs[(w * 32 + mi * 16 + qd * 4 + r) * 72 + c * 16 + l15] = f2bs(pv);
                    }
            }
            asm volatile("s_waitcnt lgkmcnt(0)" ::: "memory");
            #pragma unroll
            for (int t = 0; t < 2; ++t) {
                bf16x8 ap0 = *(const bf16x8*)&Qs[(w * 32 + l15) * 72 + t * 32 + qd * 8];
                bf16x8 ap1 = *(const bf16x8*)&Qs[(w * 32 + 16 + l15) * 72 + t * 32 + qd * 8];
                #pragma unroll
                for (int c = 0; c < 4; ++c) {
                    bf16x8 bv = *(const bf16x8*)&Vt[p][(c * 16 + l15) * 72 + t * 32 + qd * 8];
                    oacc[0][c] = mfma16(ap0, bv, oacc[0][c]);
                    oacc[1][c] = mfma16(ap1, bv, oacc[1][c]);
                }
            }
            if (pre) {
                *(bf16x8*)&Ks[1 - p][r0s * 72 + c0s] = kr0;
                *(bf16x8*)&Ks[1 - p][r1s * 72 + c0s] = kr1;
                *(bf16x8*)&Vt[1 - p][r0s * 72 + c0s] = vr0;
                *(bf16x8*)&Vt[1 - p][r1s * 72 + c0s] = vr1;
            }
            __syncthreads();
            p ^= 1;
        }

        #pragma unroll
        for (int mi = 0; mi < 2; ++mi) {
            float inv[4];
            #pragma unroll
            for (int r = 0; r < 4; ++r) {
                float l = lrow[mi][r];
                l += __shfl_xor(l, 1);
                l += __shfl_xor(l, 2);
                l += __shfl_xor(l, 4);
                l += __shfl_xor(l, 8);
                inv[r] = 1.f / l;
            }
            #pragma unroll
            for (int c = 0; c < 4; ++c)
                #pragma unroll
                for (int r = 0; r < 4; ++r) {
                    int s = qt * 128 + w * 32 + mi * 16 + qd * 4 + r;
                    Ow[((size_t)b * S_ + s) * (H_ * D_) + h * D_ + c * 16 + l15] =
                        f2bs(oacc[mi][c][r] * inv[r]);
                }
        }
    }
}

// ---------------------------------------------------------------------------
// Output projection, 32x32x16 MFMA. Block 128x128, wave 64x64 (2x2 frag32),
// BK=64 global_load_lds into double-buffered LDS, counted vmcnt(8), raw
// barriers, 2-deep prefetch.
// ---------------------------------------------------------------------------
__global__ __launch_bounds__(256, 2) void out_proj(
    const short* __restrict__ Oin, const short* __restrict__ WpT,
    const float* __restrict__ bp, float* __restrict__ out)
{
    const int m0 = blockIdx.x * 128;
    const int n0 = blockIdx.y * 128;
    __shared__ short SM2[2 * PBUF];               // 64 KB: two 32 KB buffers

    const int tid = threadIdx.x;
    const int lane = tid & 63, w = tid >> 6;
    const int wm = w & 1, wn = w >> 1;
    const int l31 = lane & 31, hi = lane >> 5;

    f32x16 acc[2][2];
    #pragma unroll
    for (int mf = 0; mf < 2; ++mf)
        #pragma unroll
        for (int nf = 0; nf < 2; ++nf)
            #pragma unroll
            for (int i = 0; i < 16; ++i) acc[mf][nf][i] = 0.f;

    auto stage = [&](int kt, int pb) {
        const int k0 = kt * 64;
        short* As = SM2 + pb * PBUF;
        short* Bs = As + 8 * PSLAB;
        #pragma unroll
        for (int it = 0; it < 4; ++it) {
            const int u = it * 256 + tid;
            const int s = u >> 7, r = u & 127;
            const int ub = it * 256 + (tid & 192);
            const int lo = (ub >> 7) * PSLAB + (ub & 127) * 8;
            gl16(&Oin[(size_t)(m0 + r) * E_ + k0 + s * 8], &As[lo]);
            gl16(&WpT[(size_t)(n0 + r) * E_ + k0 + s * 8], &Bs[lo]);
        }
    };

    stage(0, 0);
    stage(1, 1);
    __builtin_amdgcn_sched_barrier(0);

    int p = 0;
    for (int kt = 0; kt < 16; ++kt) {
        if (kt < 15) { asm volatile("s_waitcnt vmcnt(8)" ::: "memory"); }
        else         { asm volatile("s_waitcnt vmcnt(0)" ::: "memory"); }
        __builtin_amdgcn_sched_barrier(0);
        __builtin_amdgcn_s_barrier();
        __builtin_amdgcn_sched_barrier(0);

        const short* As = SM2 + p * PBUF;
        const short* Bs = As + 8 * PSLAB;
        __builtin_amdgcn_s_setprio(1);
        #pragma unroll
        for (int ks = 0; ks < 4; ++ks) {
            const int ccr = ks * 2 + hi;
            bf16x8 a[2], b[2];
            #pragma unroll
            for (int mf = 0; mf < 2; ++mf)
                a[mf] = *(const bf16x8*)&As[ccr * PSLAB + (wm * 64 + mf * 32 + l31) * 8];
            #pragma unroll
            for (int nf = 0; nf < 2; ++nf)
                b[nf] = *(const bf16x8*)&Bs[ccr * PSLAB + (wn * 64 + nf * 32 + l31) * 8];
            #pragma unroll
            for (int mf = 0; mf < 2; ++mf)
                #pragma unroll
                for (int nf = 0; nf < 2; ++nf)
                    acc[mf][nf] = mfma32(a[mf], b[nf], acc[mf][nf]);
        }
        __builtin_amdgcn_s_setprio(0);
        __builtin_amdgcn_sched_barrier(0);
        __builtin_amdgcn_s_barrier();
        __builtin_amdgcn_sched_barrier(0);
        if (kt + 2 < 16) stage(kt + 2, p);
        __builtin_amdgcn_sched_barrier(0);
        p ^= 1;
    }

    #pragma unroll
    for (int mf = 0; mf < 2; ++mf)
        #pragma unroll
        for (int nf = 0; nf < 2; ++nf) {
            const int n = n0 + wn * 64 + nf * 32 + l31;
            const float bpv = bp[n];
            const int sl0 = wm * 64 + mf * 32 + 4 * hi;
            #pragma unroll
            for (int rg = 0; rg < 16; ++rg) {
                int m = m0 + sl0 + (rg & 3) + 8 * (rg >> 2);
                out[(size_t)m * E_ + n] = acc[mf][nf][rg] + bpv;
            }
        }
}

// ---------------------------------------------------------------------------
extern "C" void kernel_launch(void* const* d_in, const int* in_sizes, int n_in,
                              void* d_out, int out_size, void* d_ws, size_t ws_size,
                              hipStream_t stream)
{
    const float* x  = (const float*)d_in[0];
    const float* Wq = (const float*)d_in[1];
    const float* bq = (const float*)d_in[2];
    const float* Wk = (const float*)d_in[3];
    const float* bk = (const float*)d_in[4];
    const float* Wv = (const float*)d_in[5];
    const float* bv = (const float*)d_in[6];
    const float* Wp = (const float*)d_in[7];
    const float* bp = (const float*)d_in[8];
    float* out = (float*)d_out;

    const size_t nQKV = (size_t)B_ * H_ * S_ * D_;   // 8,388,608 bf16 elements
    short* Qw   = (short*)d_ws;          // [B,H,S,D]; later reused for WpT
    short* Kw   = Qw + nQKV;             // [B,H,S,D]
    short* VTw  = Kw + nQKV;             // [B,H,D,S]
    short* WT   = VTw + nQKV;            // [48][64][1024] bf16 (3,145,728 shorts)
    short* xb   = WT + (size_t)48 * 64 * E_;  // x as bf16 [8192][1024]
    short* Ow   = xb;                    // xb dead after qkv_fused; attn writes Ow here
    short* WpT  = Qw;                    // Qw dead after attn

    conv_wqkv<<<dim3(1792), 256, 0, stream>>>(Wq, Wk, Wv, WT, x, xb);
    qkv_fused<<<dim3(64, 16), 256, 0, stream>>>(xb, WT, bq, bk, bv, Qw, Kw, VTw);
    attn<<<dim3(8, 64), 256, 0, stream>>>(Qw, Kw, VTw, Ow);
    conv_wp<<<dim3(256), 256, 0, stream>>>(Wp, WpT);
    out_proj<<<dim3(64, 8), 256, 0, stream>>>(Ow, WpT, bp, out);
}

// Round 6
// 243.875 us; speedup vs baseline: 1.2129x; 1.1918x over previous
//
#include <hip/hip_runtime.h>
#include <hip/hip_bf16.h>

#define B_ 4
#define S_ 2048
#define E_ 1024
#define H_ 16
#define D_ 64
#define QSCALE 0.18033688011112042f  // (1/8) * log2(e) : softmax in exp2 domain

typedef __attribute__((ext_vector_type(8))) short bf16x8;   // 8 bf16 (4 VGPRs)
typedef __attribute__((ext_vector_type(4))) float f32x4;    // 16x16 C/D frag
typedef __attribute__((ext_vector_type(16))) float f32x16;  // 32x32 C/D frag

__device__ __forceinline__ f32x4 mfma16(bf16x8 a, bf16x8 b, f32x4 c) {
    return __builtin_amdgcn_mfma_f32_16x16x32_bf16(a, b, c, 0, 0, 0);
}
__device__ __forceinline__ f32x16 mfma32(bf16x8 a, bf16x8 b, f32x16 c) {
    return __builtin_amdgcn_mfma_f32_32x32x16_bf16(a, b, c, 0, 0, 0);
}
__device__ __forceinline__ short f2bs(float f) {
    __hip_bfloat16 h = __float2bfloat16(f);
    return *reinterpret_cast<short*>(&h);
}

// slab strides (shorts). Slab = one 8-wide k-chunk of all rows. Stride chosen
// so slab-to-slab offset == 4 words mod 32 banks -> staging writes conflict-free.
#define XSLAB 1032   // 128 rows * 8 + 8 pad
#define WSLAB 1544   // 192 rows * 8 + 8 pad

// ---------------------------------------------------------------------------
// One conversion kernel, 2048 blocks:
//   [0,768)    : transpose-convert Wq/Wk/Wv -> WT[48][64][1024] bf16
//   [768,1792) : convert x [8192][1024] fp32 -> xb bf16
//   [1792,2048): transpose-convert Wp [1024][1024] fp32 -> WpT[n][k] bf16
// ---------------------------------------------------------------------------
__global__ __launch_bounds__(256) void conv_all(
    const float* __restrict__ Wq, const float* __restrict__ Wk,
    const float* __restrict__ Wv, short* __restrict__ WT,
    const float* __restrict__ x, short* __restrict__ xb,
    const float* __restrict__ Wp, short* __restrict__ WpT)
{
    __shared__ float T[64][65];
    const int tid = threadIdx.x;
    const int bid = blockIdx.x;
    if (bid >= 768 && bid < 1792) {
        const int c = bid - 768;
        const float* xs = x + (size_t)c * 8192;
        short* xd = xb + (size_t)c * 8192;
        #pragma unroll
        for (int it = 0; it < 4; ++it) {
            const int off = it * 2048 + tid * 8;
            const float4 a = *(const float4*)&xs[off];
            const float4 b = *(const float4*)&xs[off + 4];
            bf16x8 pk;
            pk[0] = f2bs(a.x); pk[1] = f2bs(a.y); pk[2] = f2bs(a.z); pk[3] = f2bs(a.w);
            pk[4] = f2bs(b.x); pk[5] = f2bs(b.y); pk[6] = f2bs(b.z); pk[7] = f2bs(b.w);
            *(bf16x8*)&xd[off] = pk;
        }
        return;
    }
    if (bid < 768) {
        const int mat = bid >> 4;
        const int kt  = bid & 15;
        const int which = mat >> 4, h = mat & 15;
        const float* src = (which == 0 ? Wq : which == 1 ? Wk : Wv) + (size_t)h * E_ * D_;
        const int k0 = kt * 64;
        #pragma unroll
        for (int it = 0; it < 4; ++it) {
            int lin = tid + it * 256;
            int kr = lin >> 4, dc = (lin & 15) * 4;
            const float4 v = *(const float4*)&src[(size_t)(k0 + kr) * D_ + dc];
            T[kr][dc] = v.x; T[kr][dc + 1] = v.y; T[kr][dc + 2] = v.z; T[kr][dc + 3] = v.w;
        }
        __syncthreads();
        #pragma unroll
        for (int it = 0; it < 4; ++it) {
            int lin = tid + it * 256;
            int dr = lin >> 4, kc = (lin & 15) * 4;
            ushort4 o;
            o.x = (unsigned short)f2bs(T[kc][dr]);
            o.y = (unsigned short)f2bs(T[kc + 1][dr]);
            o.z = (unsigned short)f2bs(T[kc + 2][dr]);
            o.w = (unsigned short)f2bs(T[kc + 3][dr]);
            *(ushort4*)&WT[((size_t)mat * 64 + dr) * E_ + k0 + kc] = o;
        }
        return;
    }
    // Wp transpose
    const int idx = bid - 1792;
    const int ktile = idx & 15, ntile = idx >> 4;
    const int k0 = ktile * 64, n0 = ntile * 64;
    #pragma unroll
    for (int it = 0; it < 4; ++it) {
        int lin = tid + it * 256;
        int kr = lin >> 4, nc = (lin & 15) * 4;
        const float4 v = *(const float4*)&Wp[(size_t)(k0 + kr) * E_ + n0 + nc];
        T[kr][nc] = v.x; T[kr][nc + 1] = v.y; T[kr][nc + 2] = v.z; T[kr][nc + 3] = v.w;
    }
    __syncthreads();
    #pragma unroll
    for (int it = 0; it < 4; ++it) {
        int lin = tid + it * 256;
        int nr = lin >> 4, kc = (lin & 15) * 4;
        ushort4 o;
        o.x = (unsigned short)f2bs(T[kc][nr]);
        o.y = (unsigned short)f2bs(T[kc + 1][nr]);
        o.z = (unsigned short)f2bs(T[kc + 2][nr]);
        o.w = (unsigned short)f2bs(T[kc + 3][nr]);
        *(ushort4*)&WpT[(size_t)(n0 + nr) * E_ + k0 + kc] = o;
    }
}

// ---------------------------------------------------------------------------
// Fused QKV projection, 32x32x16 MFMA. Block 128 rows x 192 cols (3 mats),
// wave = 64 rows x 96 cols (2x3 frag32). BK=64, register-prefetch pipeline
// (r1 proven structure), chunked-K slab LDS (conflict-free). Input is
// pre-converted bf16 xb -> commit phase is pure ds_write_b128 (no cvt).
// V stored transposed [B,H,D,S].
// ---------------------------------------------------------------------------
__global__ __launch_bounds__(256, 2) void qkv_fused(
    const short* __restrict__ xb, const short* __restrict__ WT,
    const float* __restrict__ bq, const float* __restrict__ bk,
    const float* __restrict__ bv,
    short* __restrict__ Qw, short* __restrict__ Kw, short* __restrict__ VTw)
{
    const int h = blockIdx.y;
    const int m0 = blockIdx.x * 128;
    __shared__ short SM[8 * XSLAB + 8 * WSLAB];   // 41.2 KB
    short* Xs = SM;
    short* Ws = SM + 8 * XSLAB;

    const int tid = threadIdx.x;
    const int lane = tid & 63, w = tid >> 6;
    const int wm = w & 1, wn = w >> 1;            // wave m-half / n-half
    const int l31 = lane & 31, hi = lane >> 5;
    const int cc = tid & 7, r8 = tid >> 3;        // staging coords

    f32x16 acc[2][3];
    #pragma unroll
    for (int mf = 0; mf < 2; ++mf)
        #pragma unroll
        for (int nf = 0; nf < 3; ++nf)
            #pragma unroll
            for (int i = 0; i < 16; ++i) acc[mf][nf][i] = 0.f;

    bf16x8 xr[4];
    bf16x8 wr[6];

    // prologue loads (k0 = 0)
    #pragma unroll
    for (int it = 0; it < 4; ++it)
        xr[it] = *(const bf16x8*)&xb[(size_t)(m0 + it * 32 + r8) * E_ + cc * 8];
    #pragma unroll
    for (int it = 0; it < 6; ++it) {
        int rg = ((it >> 1) * 16 + h) * 64 + (it & 1) * 32 + r8;
        wr[it] = *(const bf16x8*)&WT[(size_t)rg * E_ + cc * 8];
    }

    for (int k0 = 0; k0 < E_; k0 += 64) {
        // commit staged regs -> LDS slabs (pure b128 writes, conflict-free pads)
        #pragma unroll
        for (int it = 0; it < 4; ++it)
            *(bf16x8*)&Xs[cc * XSLAB + (it * 32 + r8) * 8] = xr[it];
        #pragma unroll
        for (int it = 0; it < 6; ++it)
            *(bf16x8*)&Ws[cc * WSLAB + (it * 32 + r8) * 8] = wr[it];
        __syncthreads();
        // issue next tile's loads (latency hidden under MFMA)
        if (k0 + 64 < E_) {
            #pragma unroll
            for (int it = 0; it < 4; ++it)
                xr[it] = *(const bf16x8*)&xb[(size_t)(m0 + it * 32 + r8) * E_ + k0 + 64 + cc * 8];
            #pragma unroll
            for (int it = 0; it < 6; ++it) {
                int rg = ((it >> 1) * 16 + h) * 64 + (it & 1) * 32 + r8;
                wr[it] = *(const bf16x8*)&WT[(size_t)rg * E_ + k0 + 64 + cc * 8];
            }
        }
        // 4 k-steps x 6 mfma32
        #pragma unroll
        for (int ks = 0; ks < 4; ++ks) {
            const int ccr = ks * 2 + hi;
            bf16x8 a[2], b[3];
            #pragma unroll
            for (int mf = 0; mf < 2; ++mf)
                a[mf] = *(const bf16x8*)&Xs[ccr * XSLAB + (wm * 64 + mf * 32 + l31) * 8];
            #pragma unroll
            for (int nf = 0; nf < 3; ++nf)
                b[nf] = *(const bf16x8*)&Ws[ccr * WSLAB + (wn * 96 + nf * 32 + l31) * 8];
            #pragma unroll
            for (int mf = 0; mf < 2; ++mf)
                #pragma unroll
                for (int nf = 0; nf < 3; ++nf)
                    acc[mf][nf] = mfma32(a[mf], b[nf], acc[mf][nf]);
        }
        __syncthreads();
    }

    // epilogue. C/D 32-shape: col=l31, row=(reg&3)+8*(reg>>2)+4*hi
    const int bb = m0 >> 11;
    const int s0 = m0 & (S_ - 1);
    const size_t qkbase = ((size_t)bb * H_ + h) * S_;
    short* Vr = SM;                                // reuse (size 64*136 shorts)
    #pragma unroll
    for (int mf = 0; mf < 2; ++mf)
        #pragma unroll
        for (int nf = 0; nf < 3; ++nf) {
            const int ng = wn * 96 + nf * 32;      // wave-uniform
            const int mat = ng >> 6;
            const int d = (ng & 63) + l31;
            const int sl0 = wm * 64 + mf * 32 + 4 * hi;
            if (mat == 0) {
                const float bb_ = bq[h * D_ + d];
                #pragma unroll
                for (int rg = 0; rg < 16; ++rg) {
                    int s = s0 + sl0 + (rg & 3) + 8 * (rg >> 2);
                    Qw[(qkbase + s) * D_ + d] = f2bs((acc[mf][nf][rg] + bb_) * QSCALE);
                }
            } else if (mat == 1) {
                const float bb_ = bk[h * D_ + d];
                #pragma unroll
                for (int rg = 0; rg < 16; ++rg) {
                    int s = s0 + sl0 + (rg & 3) + 8 * (rg >> 2);
                    Kw[(qkbase + s) * D_ + d] = f2bs(acc[mf][nf][rg] + bb_);
                }
            } else {
                const float bb_ = bv[h * D_ + d];
                #pragma unroll
                for (int rg = 0; rg < 16; ++rg) {
                    int sl = sl0 + (rg & 3) + 8 * (rg >> 2);
                    Vr[d * 136 + sl] = f2bs(acc[mf][nf][rg] + bb_);
                }
            }
        }
    __syncthreads();
    const size_t vbase = ((size_t)bb * H_ + h) * (size_t)D_ * S_;
    const int sc = tid & 15, dr = tid >> 4;
    #pragma unroll
    for (int it = 0; it < 4; ++it) {
        int d = it * 16 + dr;
        *(bf16x8*)&VTw[vbase + (size_t)d * S_ + s0 + sc * 8] =
            *(const bf16x8*)&Vr[d * 136 + sc * 8];
    }
}

// ---------------------------------------------------------------------------
// Flash attention (proven version, unchanged). Fixed-max softmax, paired
// q-tiles, double-buffered K/V LDS with register prefetch.
// ---------------------------------------------------------------------------
__global__ __launch_bounds__(256, 2) void attn(
    const short* __restrict__ Qw, const short* __restrict__ Kw,
    const short* __restrict__ VTw, short* __restrict__ Ow)
{
    const int jj = blockIdx.x;                    // 0..7
    const int bh = blockIdx.y;
    const int b = bh >> 4, h = bh & 15;
    const size_t kbase = ((size_t)b * H_ + h) * (size_t)S_ * D_;
    const size_t vbase = ((size_t)b * H_ + h) * (size_t)D_ * S_;

    __shared__ short Qs[128 * 72];
    __shared__ short Ks[2][64 * 72];
    __shared__ short Vt[2][64 * 72];

    const int tid = threadIdx.x;
    const int lane = tid & 63, w = tid >> 6;
    const int l15 = lane & 15, qd = lane >> 4;

    const int r0s = tid >> 3;
    const int c0s = (tid & 7) * 8;
    const int r1s = r0s + 32;

    #pragma unroll
    for (int phase = 0; phase < 2; ++phase) {
        const int qt = phase ? jj : (15 - jj);

        #pragma unroll
        for (int it = 0; it < 4; ++it) {
            int row = w * 32 + it * 8 + (lane >> 3);
            int cb = (lane & 7) * 8;
            *(bf16x8*)&Qs[row * 72 + cb] =
                *(const bf16x8*)&Qw[kbase + (size_t)(qt * 128 + row) * D_ + cb];
        }
        asm volatile("s_waitcnt lgkmcnt(0)" ::: "memory");
        bf16x8 qf[2][2];
        #pragma unroll
        for (int mi = 0; mi < 2; ++mi)
            #pragma unroll
            for (int t = 0; t < 2; ++t)
                qf[mi][t] = *(const bf16x8*)&Qs[(w * 32 + mi * 16 + l15) * 72 + t * 32 + qd * 8];

        f32x4 zero = {0.f, 0.f, 0.f, 0.f};
        f32x4 oacc[2][4];
        float lrow[2][4];
        #pragma unroll
        for (int mi = 0; mi < 2; ++mi) {
            #pragma unroll
            for (int c = 0; c < 4; ++c) oacc[mi][c] = zero;
            #pragma unroll
            for (int r = 0; r < 4; ++r) lrow[mi][r] = 0.f;
        }

        const int nkt = (qt + 1) * 2;
        bf16x8 kr0, kr1, vr0, vr1;
        kr0 = *(const bf16x8*)&Kw[kbase + (size_t)r0s * D_ + c0s];
        kr1 = *(const bf16x8*)&Kw[kbase + (size_t)r1s * D_ + c0s];
        vr0 = *(const bf16x8*)&VTw[vbase + (size_t)r0s * S_ + c0s];
        vr1 = *(const bf16x8*)&VTw[vbase + (size_t)r1s * S_ + c0s];
        *(bf16x8*)&Ks[0][r0s * 72 + c0s] = kr0;
        *(bf16x8*)&Ks[0][r1s * 72 + c0s] = kr1;
        *(bf16x8*)&Vt[0][r0s * 72 + c0s] = vr0;
        *(bf16x8*)&Vt[0][r1s * 72 + c0s] = vr1;
        __syncthreads();

        int p = 0;
        for (int kt = 0; kt < nkt; ++kt) {
            const bool pre = (kt + 1 < nkt);
            if (pre) {
                kr0 = *(const bf16x8*)&Kw[kbase + (size_t)((kt + 1) * 64 + r0s) * D_ + c0s];
                kr1 = *(const bf16x8*)&Kw[kbase + (size_t)((kt + 1) * 64 + r1s) * D_ + c0s];
                vr0 = *(const bf16x8*)&VTw[vbase + (size_t)r0s * S_ + (kt + 1) * 64 + c0s];
                vr1 = *(const bf16x8*)&VTw[vbase + (size_t)r1s * S_ + (kt + 1) * 64 + c0s];
            }
            f32x4 sc[2][4];
            #pragma unroll
            for (int mi = 0; mi < 2; ++mi)
                #pragma unroll
                for (int c = 0; c < 4; ++c) sc[mi][c] = zero;
            #pragma unroll
            for (int t = 0; t < 2; ++t)
                #pragma unroll
                for (int c = 0; c < 4; ++c) {
                    bf16x8 bk = *(const bf16x8*)&Ks[p][(c * 16 + l15) * 72 + t * 32 + qd * 8];
                    sc[0][c] = mfma16(qf[0][t], bk, sc[0][c]);
                    sc[1][c] = mfma16(qf[1][t], bk, sc[1][c]);
                }
            #pragma unroll
            for (int mi = 0; mi < 2; ++mi) {
                const int fr = qt * 128 + w * 32 + mi * 16;
                if (kt * 64 + 63 > fr) {
                    #pragma unroll
                    for (int c = 0; c < 4; ++c) {
                        int col = kt * 64 + c * 16 + l15;
                        #pragma unroll
                        for (int r = 0; r < 4; ++r)
                            if (col > fr + qd * 4 + r) sc[mi][c][r] = -1e30f;
                    }
                }
                #pragma unroll
                for (int c = 0; c < 4; ++c)
                    #pragma unroll
                    for (int r = 0; r < 4; ++r) {
                        float pv = __builtin_amdgcn_exp2f(sc[mi][c][r]);
                        lrow[mi][r] += pv;
                        Qs[(w * 32 + mi * 16 + qd * 4 + r) * 72 + c * 16 + l15] = f2bs(pv);
                    }
            }
            asm volatile("s_waitcnt lgkmcnt(0)" ::: "memory");
            #pragma unroll
            for (int t = 0; t < 2; ++t) {
                bf16x8 ap0 = *(const bf16x8*)&Qs[(w * 32 + l15) * 72 + t * 32 + qd * 8];
                bf16x8 ap1 = *(const bf16x8*)&Qs[(w * 32 + 16 + l15) * 72 + t * 32 + qd * 8];
                #pragma unroll
                for (int c = 0; c < 4; ++c) {
                    bf16x8 bv = *(const bf16x8*)&Vt[p][(c * 16 + l15) * 72 + t * 32 + qd * 8];
                    oacc[0][c] = mfma16(ap0, bv, oacc[0][c]);
                    oacc[1][c] = mfma16(ap1, bv, oacc[1][c]);
                }
            }
            if (pre) {
                *(bf16x8*)&Ks[1 - p][r0s * 72 + c0s] = kr0;
                *(bf16x8*)&Ks[1 - p][r1s * 72 + c0s] = kr1;
                *(bf16x8*)&Vt[1 - p][r0s * 72 + c0s] = vr0;
                *(bf16x8*)&Vt[1 - p][r1s * 72 + c0s] = vr1;
            }
            __syncthreads();
            p ^= 1;
        }

        #pragma unroll
        for (int mi = 0; mi < 2; ++mi) {
            float inv[4];
            #pragma unroll
            for (int r = 0; r < 4; ++r) {
                float l = lrow[mi][r];
                l += __shfl_xor(l, 1);
                l += __shfl_xor(l, 2);
                l += __shfl_xor(l, 4);
                l += __shfl_xor(l, 8);
                inv[r] = 1.f / l;
            }
            #pragma unroll
            for (int c = 0; c < 4; ++c)
                #pragma unroll
                for (int r = 0; r < 4; ++r) {
                    int s = qt * 128 + w * 32 + mi * 16 + qd * 4 + r;
                    Ow[((size_t)b * S_ + s) * (H_ * D_) + h * D_ + c * 16 + l15] =
                        f2bs(oacc[mi][c][r] * inv[r]);
                }
        }
    }
}

// ---------------------------------------------------------------------------
// Output projection, 32x32x16 MFMA. Block 128x128, wave 64x64 (2x2 frag32),
// BK=64, register-prefetch, chunked-K slab LDS (r1 proven structure).
// ---------------------------------------------------------------------------
__global__ __launch_bounds__(256, 2) void out_proj(
    const short* __restrict__ Oin, const short* __restrict__ WpT,
    const float* __restrict__ bp, float* __restrict__ out)
{
    const int m0 = blockIdx.x * 128;
    const int n0 = blockIdx.y * 128;
    __shared__ short SM2[16 * XSLAB];             // A slabs + B slabs, 33 KB
    short* As = SM2;
    short* Bs = SM2 + 8 * XSLAB;

    const int tid = threadIdx.x;
    const int lane = tid & 63, w = tid >> 6;
    const int wm = w & 1, wn = w >> 1;
    const int l31 = lane & 31, hi = lane >> 5;
    const int cc = tid & 7, r8 = tid >> 3;

    f32x16 acc[2][2];
    #pragma unroll
    for (int mf = 0; mf < 2; ++mf)
        #pragma unroll
        for (int nf = 0; nf < 2; ++nf)
            #pragma unroll
            for (int i = 0; i < 16; ++i) acc[mf][nf][i] = 0.f;

    bf16x8 ar[4], br[4];
    #pragma unroll
    for (int it = 0; it < 4; ++it) {
        ar[it] = *(const bf16x8*)&Oin[(size_t)(m0 + it * 32 + r8) * E_ + cc * 8];
        br[it] = *(const bf16x8*)&WpT[(size_t)(n0 + it * 32 + r8) * E_ + cc * 8];
    }

    for (int k0 = 0; k0 < E_; k0 += 64) {
        #pragma unroll
        for (int it = 0; it < 4; ++it) {
            *(bf16x8*)&As[cc * XSLAB + (it * 32 + r8) * 8] = ar[it];
            *(bf16x8*)&Bs[cc * XSLAB + (it * 32 + r8) * 8] = br[it];
        }
        __syncthreads();
        if (k0 + 64 < E_) {
            #pragma unroll
            for (int it = 0; it < 4; ++it) {
                ar[it] = *(const bf16x8*)&Oin[(size_t)(m0 + it * 32 + r8) * E_ + k0 + 64 + cc * 8];
                br[it] = *(const bf16x8*)&WpT[(size_t)(n0 + it * 32 + r8) * E_ + k0 + 64 + cc * 8];
            }
        }
        #pragma unroll
        for (int ks = 0; ks < 4; ++ks) {
            const int ccr = ks * 2 + hi;
            bf16x8 a[2], b[2];
            #pragma unroll
            for (int mf = 0; mf < 2; ++mf)
                a[mf] = *(const bf16x8*)&As[ccr * XSLAB + (wm * 64 + mf * 32 + l31) * 8];
            #pragma unroll
            for (int nf = 0; nf < 2; ++nf)
                b[nf] = *(const bf16x8*)&Bs[ccr * XSLAB + (wn * 64 + nf * 32 + l31) * 8];
            #pragma unroll
            for (int mf = 0; mf < 2; ++mf)
                #pragma unroll
                for (int nf = 0; nf < 2; ++nf)
                    acc[mf][nf] = mfma32(a[mf], b[nf], acc[mf][nf]);
        }
        __syncthreads();
    }
    #pragma unroll
    for (int mf = 0; mf < 2; ++mf)
        #pragma unroll
        for (int nf = 0; nf < 2; ++nf) {
            const int n = n0 + wn * 64 + nf * 32 + l31;
            const float bpv = bp[n];
            const int sl0 = wm * 64 + mf * 32 + 4 * hi;
            #pragma unroll
            for (int rg = 0; rg < 16; ++rg) {
                int m = m0 + sl0 + (rg & 3) + 8 * (rg >> 2);
                out[(size_t)m * E_ + n] = acc[mf][nf][rg] + bpv;
            }
        }
}

// ---------------------------------------------------------------------------
extern "C" void kernel_launch(void* const* d_in, const int* in_sizes, int n_in,
                              void* d_out, int out_size, void* d_ws, size_t ws_size,
                              hipStream_t stream)
{
    const float* x  = (const float*)d_in[0];
    const float* Wq = (const float*)d_in[1];
    const float* bq = (const float*)d_in[2];
    const float* Wk = (const float*)d_in[3];
    const float* bk = (const float*)d_in[4];
    const float* Wv = (const float*)d_in[5];
    const float* bv = (const float*)d_in[6];
    const float* Wp = (const float*)d_in[7];
    const float* bp = (const float*)d_in[8];
    float* out = (float*)d_out;

    const size_t nQKV = (size_t)B_ * H_ * S_ * D_;   // 8,388,608 bf16 elements
    short* Qw   = (short*)d_ws;          // [B,H,S,D]
    short* Kw   = Qw + nQKV;             // [B,H,S,D]
    short* VTw  = Kw + nQKV;             // [B,H,D,S]
    short* WT   = VTw + nQKV;            // [48][64][1024] bf16 (3,145,728 shorts)
    short* xb   = WT + (size_t)48 * 64 * E_;  // x as bf16 [8192][1024]
    short* WpT  = xb + (size_t)8192 * E_;     // DEDICATED slot (was aliased to Qw -> r5 bug)
    short* Ow   = xb;                    // xb dead after qkv_fused; attn writes Ow here

    conv_all<<<dim3(2048), 256, 0, stream>>>(Wq, Wk, Wv, WT, x, xb, Wp, WpT);
    qkv_fused<<<dim3(64, 16), 256, 0, stream>>>(xb, WT, bq, bk, bv, Qw, Kw, VTw);
    attn<<<dim3(8, 64), 256, 0, stream>>>(Qw, Kw, VTw, Ow);
    out_proj<<<dim3(64, 8), 256, 0, stream>>>(Ow, WpT, bp, out);
}